// Round 4
// baseline (471.118 us; speedup 1.0000x reference)
//
#include <hip/hip_runtime.h>

typedef __bf16 bf16;
typedef __bf16 bf16x8 __attribute__((ext_vector_type(8)));
typedef float  f32x4  __attribute__((ext_vector_type(4)));

#define MFMA16(a, b, c) __builtin_amdgcn_mfma_f32_16x16x32_bf16((a), (b), (c), 0, 0, 0)

// async global->LDS, 16 B per lane: lane l -> ldsbase + l*16 (wave-uniform base).
__device__ inline void gl_lds16(const bf16* g, bf16* l) {
  __builtin_amdgcn_global_load_lds(
      (const __attribute__((address_space(1))) void*)g,
      (__attribute__((address_space(3))) void*)l, 16, 0, 0);
}

__device__ inline bf16x8 cvt8(const float* __restrict__ f) {
  float4 a = *(const float4*)f;
  float4 b = *(const float4*)(f + 4);
  bf16x8 r;
  r[0] = (bf16)a.x; r[1] = (bf16)a.y; r[2] = (bf16)a.z; r[3] = (bf16)a.w;
  r[4] = (bf16)b.x; r[5] = (bf16)b.y; r[6] = (bf16)b.z; r[7] = (bf16)b.w;
  return r;
}

// ---------------------------------------------------------------------------
__global__ void cvt_f32_bf16(const float* __restrict__ src, bf16* __restrict__ dst,
                             int n8) {
  int i = blockIdx.x * 256 + threadIdx.x;
  if (i >= n8) return;
  *(bf16x8*)(dst + (size_t)i * 8) = cvt8(src + (size_t)i * 8);
}

// ---------------------------------------------------------------------------
// FUSED QKV projection: one 128x128-tile GEMM over N = 3072 = 2048(Q) +
// 512(K) + 512(V). W rows 0..3071 are the contiguous wqb|wkb|wvb block.
// Per-n0-range (block-uniform) A/C select:
//   n0 < 2048 : A = qbf (bf16, gl_lds16)  -> Qb, ld 2048
//   n0 < 2560 : A = key_t (fp32, cvt8)    -> Kb, ld 512
//   else      : A = value (fp32, cvt8)    -> Vb, ld 512
// Grid 24x32 = 768 blocks = 3 blocks/CU (v6's KV gemm had 1/CU -> 1 wave/
// SIMD -> zero latency hiding -> 7% MfmaUtil; this is the occupancy fix).
// LDS fragment-ordered, conflict-free lane*16 reads (unchanged structure).
// ---------------------------------------------------------------------------
__global__ __launch_bounds__(256) void gemm_qkv(const bf16* __restrict__ qA,
                                                const float* __restrict__ kA,
                                                const float* __restrict__ vA,
                                                const bf16* __restrict__ W,
                                                bf16* __restrict__ Qb,
                                                bf16* __restrict__ Kb,
                                                bf16* __restrict__ Vb) {
  __shared__ alignas(16) bf16 As[16 * 512];   // 16 KB, fragment-ordered
  __shared__ alignas(16) bf16 Bs[16 * 512];

  const int tid  = threadIdx.x;
  const int wave = tid >> 6, lane = tid & 63;
  const int wm = wave >> 1, wn = wave & 1;
  const int lr = lane & 15, quad = lane >> 4;
  const int m0 = blockIdx.y * 128, n0 = blockIdx.x * 128;
  const int K = 2048;

  const int range = (n0 < 2048) ? 0 : (n0 < 2560) ? 1 : 2;
  const float* Af = (range == 1) ? kA : vA;

  f32x4 vzero = {0.f, 0.f, 0.f, 0.f};
  f32x4 acc[4][4];
#pragma unroll
  for (int mt = 0; mt < 4; ++mt)
#pragma unroll
    for (int nt = 0; nt < 4; ++nt) acc[mt][nt] = vzero;

  for (int k0 = 0; k0 < K; k0 += 64) {
    // ---- stage B frags (wave w: chunks 4w..4w+3) ----
#pragma unroll
    for (int j = 0; j < 4; ++j) {
      int c = wave * 4 + j;               // frag id: mi = c>>1, s = c&1
      gl_lds16(W + (size_t)(n0 + (c >> 1) * 16 + lr) * K + k0 + (c & 1) * 32 + quad * 8,
               Bs + c * 512);
    }
    // ---- stage A frags ----
    if (range == 0) {
#pragma unroll
      for (int j = 0; j < 4; ++j) {
        int c = wave * 4 + j;
        gl_lds16(qA + (size_t)(m0 + (c >> 1) * 16 + lr) * K +
                     k0 + (c & 1) * 32 + quad * 8,
                 As + c * 512);
      }
    } else {
#pragma unroll
      for (int j = 0; j < 4; ++j) {
        int c = wave * 4 + j;
        *(bf16x8*)(As + c * 512 + lane * 8) =
            cvt8(Af + (size_t)(m0 + (c >> 1) * 16 + lr) * K +
                 k0 + (c & 1) * 32 + quad * 8);
      }
    }
    __syncthreads();

#pragma unroll
    for (int s = 0; s < 2; ++s) {
      bf16x8 af[4], bfg[4];
#pragma unroll
      for (int mt = 0; mt < 4; ++mt)
        af[mt] = *(const bf16x8*)(As + ((wm * 4 + mt) * 2 + s) * 512 + lane * 8);
#pragma unroll
      for (int nt = 0; nt < 4; ++nt)
        bfg[nt] = *(const bf16x8*)(Bs + ((wn * 4 + nt) * 2 + s) * 512 + lane * 8);
#pragma unroll
      for (int mt = 0; mt < 4; ++mt)
#pragma unroll
        for (int nt = 0; nt < 4; ++nt)
          acc[mt][nt] = MFMA16(af[mt], bfg[nt], acc[mt][nt]);
    }
    __syncthreads();
  }

  // epilogue: C/D layout col = lane&15, row = quad*4 + e   [HW-verified m89]
  bf16* Cb = (range == 0) ? Qb : (range == 1) ? Kb : Vb;
  const int ld = (range == 0) ? 2048 : 512;
  const int nb = (range == 0) ? n0 : (range == 1) ? n0 - 2048 : n0 - 2560;
#pragma unroll
  for (int mt = 0; mt < 4; ++mt) {
    int row = m0 + wm * 64 + mt * 16 + quad * 4;
#pragma unroll
    for (int nt = 0; nt < 4; ++nt) {
      int col = nb + wn * 64 + nt * 16 + lr;
#pragma unroll
      for (int e = 0; e < 4; ++e)
        Cb[(size_t)(row + e) * ld + col] = (bf16)acc[mt][nt][e];
    }
  }
}

// ---------------------------------------------------------------------------
// GEMM: C[M,N] = A[M,K] @ W[N,K]^T, bf16 MFMA, fp32 accum. (O-projection)
// 128x128 tile, BK=64, 4 waves (2x2), 4x4 16x16x32 MFMA per wave.
// LDS in MFMA-FRAGMENT ORDER; fragment reads conflict-free lane*16.
// ---------------------------------------------------------------------------
template <bool OUTF32>
__global__ __launch_bounds__(256) void gemm_bt(const bf16* __restrict__ Ap,
                                               const bf16* __restrict__ W,
                                               void* __restrict__ C0,
                                               int ld0, int M, int N, int K) {
  __shared__ alignas(16) bf16 As[16 * 512];   // 16 KB, fragment-ordered
  __shared__ alignas(16) bf16 Bs[16 * 512];

  const int tid  = threadIdx.x;
  const int wave = tid >> 6, lane = tid & 63;
  const int wm = wave >> 1, wn = wave & 1;
  const int lr = lane & 15, quad = lane >> 4;
  const int m0 = blockIdx.y * 128, n0 = blockIdx.x * 128;

  f32x4 vzero = {0.f, 0.f, 0.f, 0.f};
  f32x4 acc[4][4];
#pragma unroll
  for (int mt = 0; mt < 4; ++mt)
#pragma unroll
    for (int nt = 0; nt < 4; ++nt) acc[mt][nt] = vzero;

  for (int k0 = 0; k0 < K; k0 += 64) {
#pragma unroll
    for (int j = 0; j < 4; ++j) {
      int c = wave * 4 + j;               // frag id: mi = c>>1, s = c&1
      gl_lds16(W + (size_t)(n0 + (c >> 1) * 16 + lr) * K + k0 + (c & 1) * 32 + quad * 8,
               Bs + c * 512);
      gl_lds16(Ap + (size_t)(m0 + (c >> 1) * 16 + lr) * K + k0 + (c & 1) * 32 + quad * 8,
               As + c * 512);
    }
    __syncthreads();

#pragma unroll
    for (int s = 0; s < 2; ++s) {
      bf16x8 af[4], bfg[4];
#pragma unroll
      for (int mt = 0; mt < 4; ++mt)
        af[mt] = *(const bf16x8*)(As + ((wm * 4 + mt) * 2 + s) * 512 + lane * 8);
#pragma unroll
      for (int nt = 0; nt < 4; ++nt)
        bfg[nt] = *(const bf16x8*)(Bs + ((wn * 4 + nt) * 2 + s) * 512 + lane * 8);
#pragma unroll
      for (int mt = 0; mt < 4; ++mt)
#pragma unroll
        for (int nt = 0; nt < 4; ++nt)
          acc[mt][nt] = MFMA16(af[mt], bfg[nt], acc[mt][nt]);
    }
    __syncthreads();
  }

  // epilogue: C/D layout col = lane&15, row = quad*4 + e   [HW-verified m89]
#pragma unroll
  for (int mt = 0; mt < 4; ++mt) {
    int row = m0 + wm * 64 + mt * 16 + quad * 4;
#pragma unroll
    for (int nt = 0; nt < 4; ++nt) {
      int col = n0 + wn * 64 + nt * 16 + lr;
#pragma unroll
      for (int e = 0; e < 4; ++e) {
        if (OUTF32)
          ((float*)C0)[(size_t)(row + e) * ld0 + col] = acc[mt][nt][e];
        else
          ((bf16*)C0)[(size_t)(row + e) * ld0 + col] = (bf16)acc[mt][nt][e];
      }
    }
  }
}

// ---------------------------------------------------------------------------
// RoPE + clip (+scale fold), in place, vectorized: 8 (j,j+64) pairs/thread.
// ---------------------------------------------------------------------------
__global__ void rope_clip(bf16* __restrict__ X, int heads, float scl) {
  int tpr = heads * 8;
  int idx = blockIdx.x * 256 + threadIdx.x;
  if (idx >= 4096 * tpr) return;
  int r = idx / tpr;
  int rem = idx - r * tpr;
  int h = rem >> 3, j0 = (rem & 7) * 8;
  int l = r & 2047;
  size_t base = (size_t)r * (heads * 128) + h * 128 + j0;
  bf16x8 x1 = *(const bf16x8*)(X + base);
  bf16x8 x2 = *(const bf16x8*)(X + base + 64);
  bf16x8 y1, y2;
#pragma unroll
  for (int t = 0; t < 8; ++t) {
    int j = j0 + t;
    float inv = expf(-(float)j * (9.210340371976184f / 64.0f));
    float s, c;
    sincosf((float)l * inv, &s, &c);
    float a = (float)x1[t], b = (float)x2[t];
    float u = a * c - b * s;
    float v = a * s + b * c;
    y1[t] = (bf16)(fminf(fmaxf(u, -50.f), 50.f) * scl);
    y2[t] = (bf16)(fminf(fmaxf(v, -50.f), 50.f) * scl);
  }
  *(bf16x8*)(X + base)      = y1;
  *(bf16x8*)(X + base + 64) = y2;
}

// ---------------------------------------------------------------------------
// Transpose per batch: in (R x Cc) -> out (Cc x R).
// ---------------------------------------------------------------------------
__global__ void transpose_bf16(const bf16* __restrict__ in, bf16* __restrict__ out,
                               int R, int Cc) {
  __shared__ bf16 t[32][33];
  int b = blockIdx.z;
  const bf16* ip = in + (size_t)b * R * Cc;
  bf16* op = out + (size_t)b * R * Cc;
  int c0 = blockIdx.x * 32, r0 = blockIdx.y * 32;
  int lx = threadIdx.x, ly = threadIdx.y;
#pragma unroll
  for (int i = 0; i < 32; i += 8)
    t[ly + i][lx] = ip[(size_t)(r0 + ly + i) * Cc + c0 + lx];
  __syncthreads();
#pragma unroll
  for (int i = 0; i < 32; i += 8)
    op[(size_t)(c0 + ly + i) * R + r0 + lx] = t[lx][ly + i];
}

// ---------------------------------------------------------------------------
// Flash v6, causal, GQA (16 qh -> 4 kvh), DK=128, L=2048.
// UNIFORM-WORK PAIRED BLOCKS + 2-PHASE COUNTED-vmcnt PIPELINE.
// Each block owns the q-tile pair (qt=p, qt=15-p): 8 waves, each wave has
// 16 rows of tile A and 16 rows of tile B. One k-loop to kmaxB; tile A
// rides along while active, sharing the staged K/V chunk AND the kf/vf
// fragment reads. 256 blocks of UNIFORM work = exactly 1/CU.
// K/V double-buffered; STAGE(next) issued BEFORE compute with counted
// s_waitcnt vmcnt(4) + raw s_barrier -> stage latency hides under compute.
// LDS: 64KB K/V dbuf + 36KB P (32 rows/wave, stride 72) = 100KB, 1 blk/CU.
// ---------------------------------------------------------------------------
__global__ __launch_bounds__(512, 2) void flash(const bf16* __restrict__ Q,
                                                const bf16* __restrict__ Kp,
                                                const bf16* __restrict__ Vt,
                                                bf16* __restrict__ Ctx) {
  __shared__ alignas(16) bf16 Ks[2][16 * 512];   // 2 x 16 KB
  __shared__ alignas(16) bf16 Vs[2][16 * 512];   // 2 x 16 KB
  __shared__ alignas(16) bf16 Ps[8][32 * 72];    // 36 KB

  const int tid  = threadIdx.x;
  const int wave = tid >> 6, lane = tid & 63;
  const int lr = lane & 15, quad = lane >> 4;
  const int bh = blockIdx.y;
  const int b = bh >> 4, h = bh & 15, hk = h >> 2;
  const int p = blockIdx.x;                     // 0..7 -> pair (p, 15-p)
  const int qA0 = p * 128, qB0 = (15 - p) * 128;
  const int qbA = qA0 + wave * 16;              // wave's rows in tile A
  const int qbB = qB0 + wave * 16;              // wave's rows in tile B
  const int nt = (qB0 + 128) >> 6;              // 32 - 2p chunk iterations

  // Q fragments for both tiles
  bf16x8 qfA[4], qfB[4];
  {
    const bf16* qa = Q + ((size_t)(b * 2048 + qbA + lr)) * 2048 + h * 128 + quad * 8;
    const bf16* qbp = Q + ((size_t)(b * 2048 + qbB + lr)) * 2048 + h * 128 + quad * 8;
#pragma unroll
    for (int ks = 0; ks < 4; ++ks) {
      qfA[ks] = *(const bf16x8*)(qa + ks * 32);
      qfB[ks] = *(const bf16x8*)(qbp + ks * 32);
    }
  }

  f32x4 vzero = {0.f, 0.f, 0.f, 0.f};
  f32x4 oA[8], oB[8];
#pragma unroll
  for (int dt = 0; dt < 8; ++dt) { oA[dt] = vzero; oB[dt] = vzero; }
  float flsA[4] = {0.f, 0.f, 0.f, 0.f};
  float flsB[4] = {0.f, 0.f, 0.f, 0.f};

  const bf16* kbase = Kp + (size_t)(b * 2048) * 512 + hk * 128;
  const bf16* vbase = Vt + ((size_t)(b * 512 + hk * 128)) * 2048;

  // stage 32 frag-chunks (16 K + 16 V), 4 per wave, fragment-ordered
#define STAGE(bufi, kk)                                                         \
  do {                                                                          \
    _Pragma("unroll") for (int j = 0; j < 4; ++j) {                             \
      int c = wave * 4 + j;                                                     \
      if (c < 16) {                                                             \
        gl_lds16(kbase + (size_t)((kk) + (c >> 2) * 16 + lr) * 512 +            \
                     (c & 3) * 32 + quad * 8,                                   \
                 &Ks[bufi][c * 512]);                                           \
      } else {                                                                  \
        int c2 = c - 16;                                                        \
        gl_lds16(vbase + (size_t)((c2 >> 1) * 16 + lr) * 2048 + (kk) +          \
                     (c2 & 1) * 32 + quad * 8,                                  \
                 &Vs[bufi][c2 * 512]);                                          \
      }                                                                         \
    }                                                                           \
  } while (0)

  STAGE(0, 0);  // prologue: chunk 0 -> buf 0
  int cur = 0;

  for (int t = 0; t < nt; ++t) {
    const int k0 = t * 64;
    if (t + 1 < nt) {
      STAGE(cur ^ 1, k0 + 64);  // issue next chunk before compute
      asm volatile("s_waitcnt vmcnt(4)" ::: "memory");  // wait prev chunk only
    } else {
      asm volatile("s_waitcnt vmcnt(0)" ::: "memory");
    }
    __builtin_amdgcn_s_barrier();   // all waves: chunk t fully staged

    const bf16* ksb = Ks[cur];
    const bf16* vsb = Vs[cur];

    if (k0 <= qbA + 15) {
      // ---- dual: tile A active => tile B active (and B never masked here) --
      f32x4 sA[4], sB[4];
#pragma unroll
      for (int kt = 0; kt < 4; ++kt) { sA[kt] = vzero; sB[kt] = vzero; }
#pragma unroll
      for (int ks = 0; ks < 4; ++ks) {
#pragma unroll
        for (int kt = 0; kt < 4; ++kt) {
          bf16x8 kf = *(const bf16x8*)(ksb + (kt * 4 + ks) * 512 + lane * 8);
          sA[kt] = MFMA16(qfA[ks], kf, sA[kt]);
          sB[kt] = MFMA16(qfB[ks], kf, sB[kt]);
        }
      }
      bf16* pwA = Ps[wave];
      bf16* pwB = Ps[wave] + 16 * 72;
#pragma unroll
      for (int kt = 0; kt < 4; ++kt) {
        int kid = k0 + kt * 16 + lr;
#pragma unroll
        for (int e = 0; e < 4; ++e) {
          int qr = quad * 4 + e;
          float pa = (kid <= qbA + qr) ? __expf(sA[kt][e]) : 0.f;
          float pb = __expf(sB[kt][e]);  // kid < 1024 <= qbB always
          flsA[e] += pa;
          flsB[e] += pb;
          pwA[qr * 72 + kt * 16 + lr] = (bf16)pa;
          pwB[qr * 72 + kt * 16 + lr] = (bf16)pb;
        }
      }
#pragma unroll
      for (int ks2 = 0; ks2 < 2; ++ks2) {
        bf16x8 pfA = *(const bf16x8*)(pwA + (size_t)lr * 72 + ks2 * 32 + quad * 8);
        bf16x8 pfB = *(const bf16x8*)(pwB + (size_t)lr * 72 + ks2 * 32 + quad * 8);
#pragma unroll
        for (int dt = 0; dt < 8; ++dt) {
          bf16x8 vf = *(const bf16x8*)(vsb + (dt * 2 + ks2) * 512 + lane * 8);
          oA[dt] = MFMA16(pfA, vf, oA[dt]);
          oB[dt] = MFMA16(pfB, vf, oB[dt]);
        }
      }
    } else if (k0 <= qbB + 15) {
      // ---- tile B only ----
      f32x4 s[4];
#pragma unroll
      for (int kt = 0; kt < 4; ++kt) s[kt] = vzero;
#pragma unroll
      for (int ks = 0; ks < 4; ++ks) {
#pragma unroll
        for (int kt = 0; kt < 4; ++kt) {
          bf16x8 kf = *(const bf16x8*)(ksb + (kt * 4 + ks) * 512 + lane * 8);
          s[kt] = MFMA16(qfB[ks], kf, s[kt]);
        }
      }
      bf16* pwB = Ps[wave] + 16 * 72;
#pragma unroll
      for (int kt = 0; kt < 4; ++kt) {
        int kid = k0 + kt * 16 + lr;
#pragma unroll
        for (int e = 0; e < 4; ++e) {
          int qr = quad * 4 + e;
          float pb = (kid <= qbB + qr) ? __expf(s[kt][e]) : 0.f;
          flsB[e] += pb;
          pwB[qr * 72 + kt * 16 + lr] = (bf16)pb;
        }
      }
#pragma unroll
      for (int ks2 = 0; ks2 < 2; ++ks2) {
        bf16x8 pf = *(const bf16x8*)(pwB + (size_t)lr * 72 + ks2 * 32 + quad * 8);
#pragma unroll
        for (int dt = 0; dt < 8; ++dt) {
          bf16x8 vf = *(const bf16x8*)(vsb + (dt * 2 + ks2) * 512 + lane * 8);
          oB[dt] = MFMA16(pf, vf, oB[dt]);
        }
      }
    }
    __builtin_amdgcn_s_barrier();   // all reads of buf[cur] done -> reusable
    cur ^= 1;
  }
#undef STAGE

  // denominator reduce across the 16 key-lanes
#pragma unroll
  for (int e = 0; e < 4; ++e) {
    float sa = flsA[e];
    sa += __shfl_xor(sa, 1);
    sa += __shfl_xor(sa, 2);
    sa += __shfl_xor(sa, 4);
    sa += __shfl_xor(sa, 8);
    flsA[e] = 1.0f / sa;
    float sb = flsB[e];
    sb += __shfl_xor(sb, 1);
    sb += __shfl_xor(sb, 2);
    sb += __shfl_xor(sb, 4);
    sb += __shfl_xor(sb, 8);
    flsB[e] = 1.0f / sb;
  }

  bf16* ca = Ctx + ((size_t)(b * 2048 + qbA + quad * 4)) * 2048 + h * 128 + lr;
  bf16* cb = Ctx + ((size_t)(b * 2048 + qbB + quad * 4)) * 2048 + h * 128 + lr;
#pragma unroll
  for (int dt = 0; dt < 8; ++dt)
#pragma unroll
    for (int e = 0; e < 4; ++e) {
      ca[(size_t)e * 2048 + dt * 16] = (bf16)(oA[dt][e] * flsA[e]);
      cb[(size_t)e * 2048 + dt * 16] = (bf16)(oB[dt][e] * flsB[e]);
    }
}

// ---------------------------------------------------------------------------
extern "C" void kernel_launch(void* const* d_in, const int* in_sizes, int n_in,
                              void* d_out, int out_size, void* d_ws, size_t ws_size,
                              hipStream_t stream) {
  (void)in_sizes; (void)n_in; (void)out_size; (void)ws_size;
  const float* query = (const float*)d_in[0];
  const float* key_t = (const float*)d_in[1];
  const float* value = (const float*)d_in[2];
  // d_in[3] = mask (causal tril) — applied analytically
  const float* Wq = (const float*)d_in[4];
  const float* Wk = (const float*)d_in[5];
  const float* Wv = (const float*)d_in[6];
  const float* Wo = (const float*)d_in[7];

  const size_t MB = 1024ull * 1024ull;
  char* ws  = (char*)d_ws;
  bf16* qbf = (bf16*)(ws);                  // [0,16)  query bf16
  bf16* wqb = (bf16*)(ws + 16 * MB);        // [16,24)  Wq bf16   (contiguous
  bf16* wkb = (bf16*)(ws + 24 * MB);        // [24,26)  Wk bf16    3072x2048
  bf16* wvb = (bf16*)(ws + 26 * MB);        // [26,28)  Wv bf16    W block)
  bf16* wob = (bf16*)(ws + 28 * MB);        // [28,36)
  bf16* Qb  = (bf16*)(ws + 36 * MB);        // [36,52)
  bf16* Kb  = (bf16*)(ws + 52 * MB);        // [52,56)
  bf16* Vb  = (bf16*)(ws + 56 * MB);        // [56,60)
  bf16* Vtb = (bf16*)(ws + 60 * MB);        // [60,64)
  bf16* Ctx = qbf;                          // alias: qbf dead after QKV-proj

  cvt_f32_bf16<<<4096, 256, 0, stream>>>(query, qbf, 1048576);
  cvt_f32_bf16<<<2048, 256, 0, stream>>>(Wq, wqb, 524288);
  cvt_f32_bf16<<<512, 256, 0, stream>>>(Wk, wkb, 131072);
  cvt_f32_bf16<<<512, 256, 0, stream>>>(Wv, wvb, 131072);
  cvt_f32_bf16<<<2048, 256, 0, stream>>>(Wo, wob, 524288);

  // FUSED Q+K+V projection: N=3072, 768 blocks = 3/CU
  gemm_qkv<<<dim3(24, 32), 256, 0, stream>>>(qbf, key_t, value, wqb, Qb, Kb, Vb);

  rope_clip<<<2048, 256, 0, stream>>>(Qb, 16, 0.08838834764831845f);
  rope_clip<<<512, 256, 0, stream>>>(Kb, 4, 1.0f);

  transpose_bf16<<<dim3(16, 64, 2), dim3(32, 8), 0, stream>>>(Vb, Vtb, 2048, 512);

  flash<<<dim3(8, 32), 512, 0, stream>>>(Qb, Kb, Vtb, Ctx);

  // O-projection: bf16 A (Ctx), fp32 output
  gemm_bt<true><<<dim3(16, 32), 256, 0, stream>>>(
      Ctx, wob, (float*)d_out, 2048, 4096, 2048, 2048);
}

// Round 5
// 470.417 us; speedup vs baseline: 1.0015x; 1.0015x over previous
//
#include <hip/hip_runtime.h>

typedef __bf16 bf16;
typedef __bf16 bf16x8 __attribute__((ext_vector_type(8)));
typedef float  f32x4  __attribute__((ext_vector_type(4)));

#define MFMA16(a, b, c) __builtin_amdgcn_mfma_f32_16x16x32_bf16((a), (b), (c), 0, 0, 0)

// async global->LDS, 16 B per lane: lane l -> ldsbase + l*16 (wave-uniform base).
__device__ inline void gl_lds16(const bf16* g, bf16* l) {
  __builtin_amdgcn_global_load_lds(
      (const __attribute__((address_space(1))) void*)g,
      (__attribute__((address_space(3))) void*)l, 16, 0, 0);
}

__device__ inline bf16x8 cvt8(const float* __restrict__ f) {
  float4 a = *(const float4*)f;
  float4 b = *(const float4*)(f + 4);
  bf16x8 r;
  r[0] = (bf16)a.x; r[1] = (bf16)a.y; r[2] = (bf16)a.z; r[3] = (bf16)a.w;
  r[4] = (bf16)b.x; r[5] = (bf16)b.y; r[6] = (bf16)b.z; r[7] = (bf16)b.w;
  return r;
}

__device__ inline bf16x8 cvt8v(float4 a, float4 b) {
  bf16x8 r;
  r[0] = (bf16)a.x; r[1] = (bf16)a.y; r[2] = (bf16)a.z; r[3] = (bf16)a.w;
  r[4] = (bf16)b.x; r[5] = (bf16)b.y; r[6] = (bf16)b.z; r[7] = (bf16)b.w;
  return r;
}

// ---------------------------------------------------------------------------
__global__ void cvt_f32_bf16(const float* __restrict__ src, bf16* __restrict__ dst,
                             int n8) {
  int i = blockIdx.x * 256 + threadIdx.x;
  if (i >= n8) return;
  *(bf16x8*)(dst + (size_t)i * 8) = cvt8(src + (size_t)i * 8);
}

// ---------------------------------------------------------------------------
// FUSED QKV projection, 2-PHASE COUNTED-vmcnt PIPELINE (flash-v6 pattern).
// N = 3072 = 2048(Q)+512(K)+512(V); W rows = contiguous wqb|wkb|wvb.
//   range 0 (n0<2048): A = qbf bf16, dbuf gl_lds16, vmcnt(8) counted.
//   range 1/2        : A = key_t/value fp32, 2-deep reg pipeline (issue
//                      dwordx4 for t+1 early; cvt+ds_write into nxt buf
//                      after compute, hidden under MFMA), B dbuf gl_lds16,
//                      vmcnt(12) counted. Unrolled x2, static reg names.
// v7 counters showed the drain-every-step loop pinned ALL pipes <15%
// (stage -> vmcnt(0) sync -> compute serialization); this removes it.
// LDS 64 KB (2x 16KB A + 2x 16KB B) -> 2 blocks/CU.
// ---------------------------------------------------------------------------
__global__ __launch_bounds__(256) void gemm_qkv(const bf16* __restrict__ qA,
                                                const float* __restrict__ kA,
                                                const float* __restrict__ vA,
                                                const bf16* __restrict__ W,
                                                bf16* __restrict__ Qb,
                                                bf16* __restrict__ Kb,
                                                bf16* __restrict__ Vb) {
  __shared__ alignas(16) bf16 As[2][16 * 512];   // 2 x 16 KB
  __shared__ alignas(16) bf16 Bs[2][16 * 512];   // 2 x 16 KB

  const int tid  = threadIdx.x;
  const int wave = tid >> 6, lane = tid & 63;
  const int wm = wave >> 1, wn = wave & 1;
  const int lr = lane & 15, quad = lane >> 4;
  const int m0 = blockIdx.y * 128, n0 = blockIdx.x * 128;
  const int NS = 32;                       // K/BK = 2048/64

  const int range = (n0 < 2048) ? 0 : (n0 < 2560) ? 1 : 2;
  const float* Af = (range == 1) ? kA : vA;

  f32x4 vzero = {0.f, 0.f, 0.f, 0.f};
  f32x4 acc[4][4];
#pragma unroll
  for (int mt = 0; mt < 4; ++mt)
#pragma unroll
    for (int nt = 0; nt < 4; ++nt) acc[mt][nt] = vzero;

#define BSTAGE(bufi, kk)                                                        \
  do {                                                                          \
    _Pragma("unroll") for (int j = 0; j < 4; ++j) {                             \
      int c = wave * 4 + j;                                                     \
      gl_lds16(W + (size_t)(n0 + (c >> 1) * 16 + lr) * 2048 + (kk) +            \
                   (c & 1) * 32 + quad * 8,                                     \
               &Bs[bufi][c * 512]);                                             \
    }                                                                           \
  } while (0)

#define ABSTAGE(bufi, kk)                                                       \
  do {                                                                          \
    _Pragma("unroll") for (int j = 0; j < 4; ++j) {                             \
      int c = wave * 4 + j;                                                     \
      gl_lds16(qA + (size_t)(m0 + (c >> 1) * 16 + lr) * 2048 + (kk) +           \
                   (c & 1) * 32 + quad * 8,                                     \
               &As[bufi][c * 512]);                                             \
    }                                                                           \
  } while (0)

#define AISSUE(kk, ar)                                                          \
  do {                                                                          \
    _Pragma("unroll") for (int j = 0; j < 4; ++j) {                             \
      int c = wave * 4 + j;                                                     \
      const float* ap_ = Af + (size_t)(m0 + (c >> 1) * 16 + lr) * 2048 + (kk) + \
                         (c & 1) * 32 + quad * 8;                               \
      ar[j * 2]     = *(const float4*)ap_;                                      \
      ar[j * 2 + 1] = *(const float4*)(ap_ + 4);                                \
    }                                                                           \
  } while (0)

#define AWRITE(bufi, ar)                                                        \
  do {                                                                          \
    _Pragma("unroll") for (int j = 0; j < 4; ++j) {                             \
      int c = wave * 4 + j;                                                     \
      *(bf16x8*)(&As[bufi][c * 512] + lane * 8) = cvt8v(ar[j * 2], ar[j * 2 + 1]); \
    }                                                                           \
  } while (0)

#define QKV_COMPUTE(bufi)                                                       \
  do {                                                                          \
    _Pragma("unroll") for (int s = 0; s < 2; ++s) {                             \
      bf16x8 af[4], bfg[4];                                                     \
      _Pragma("unroll") for (int mt = 0; mt < 4; ++mt)                          \
        af[mt] = *(const bf16x8*)(&As[bufi][((wm * 4 + mt) * 2 + s) * 512] +    \
                                  lane * 8);                                    \
      _Pragma("unroll") for (int nt = 0; nt < 4; ++nt)                          \
        bfg[nt] = *(const bf16x8*)(&Bs[bufi][((wn * 4 + nt) * 2 + s) * 512] +   \
                                   lane * 8);                                   \
      _Pragma("unroll") for (int mt = 0; mt < 4; ++mt)                          \
        _Pragma("unroll") for (int nt = 0; nt < 4; ++nt)                        \
          acc[mt][nt] = MFMA16(af[mt], bfg[nt], acc[mt][nt]);                   \
    }                                                                           \
  } while (0)

  if (range == 0) {
    // ---- pure-bf16 path: full dbuf gl_lds16, vmcnt(8) counted ----
    BSTAGE(0, 0);
    ABSTAGE(0, 0);
    int cur = 0;
    for (int t = 0; t < NS; ++t) {
      if (t + 1 < NS) {
        BSTAGE(cur ^ 1, (t + 1) * 64);
        ABSTAGE(cur ^ 1, (t + 1) * 64);
        asm volatile("s_waitcnt vmcnt(8)" ::: "memory");  // chunk t complete
      } else {
        asm volatile("s_waitcnt vmcnt(0)" ::: "memory");
      }
      __builtin_amdgcn_s_barrier();
      QKV_COMPUTE(cur);
      __builtin_amdgcn_s_barrier();
      cur ^= 1;
    }
  } else {
    // ---- fp32-A path: B dbuf (vmcnt(12) counted) + 2-deep A reg pipeline ----
    float4 arA[8], arB[8];
    AISSUE(0, arA);
    BSTAGE(0, 0);
    AWRITE(0, arA);                    // compiler waits arA loads; 4 ds_write
    int cur = 0;
    for (int t = 0; t < NS; t += 2) {
      // even sub-iter: compute cur; prefetch t+1 into arB / Bs[nxt]
      if (t + 1 < NS) {
        BSTAGE(cur ^ 1, (t + 1) * 64);
        AISSUE((t + 1) * 64, arB);
        asm volatile("s_waitcnt vmcnt(12)" ::: "memory");  // B(t) complete
      } else {
        asm volatile("s_waitcnt vmcnt(0)" ::: "memory");
      }
      asm volatile("s_waitcnt lgkmcnt(0)" ::: "memory");   // A ds_writes visible
      __builtin_amdgcn_s_barrier();
      QKV_COMPUTE(cur);
      if (t + 1 < NS) AWRITE(cur ^ 1, arB);                // hidden under MFMA tail
      __builtin_amdgcn_s_barrier();
      cur ^= 1;
      // odd sub-iter (NS even => always executed): compute cur; prefetch t+2
      if (t + 2 < NS) {
        BSTAGE(cur ^ 1, (t + 2) * 64);
        AISSUE((t + 2) * 64, arA);
        asm volatile("s_waitcnt vmcnt(12)" ::: "memory");
      } else {
        asm volatile("s_waitcnt vmcnt(0)" ::: "memory");
      }
      asm volatile("s_waitcnt lgkmcnt(0)" ::: "memory");
      __builtin_amdgcn_s_barrier();
      QKV_COMPUTE(cur);
      if (t + 2 < NS) AWRITE(cur ^ 1, arA);
      __builtin_amdgcn_s_barrier();
      cur ^= 1;
    }
  }
#undef BSTAGE
#undef ABSTAGE
#undef AISSUE
#undef AWRITE
#undef QKV_COMPUTE

  // epilogue: C/D layout col = lane&15, row = quad*4 + e   [HW-verified m89]
  bf16* Cb = (range == 0) ? Qb : (range == 1) ? Kb : Vb;
  const int ld = (range == 0) ? 2048 : 512;
  const int nb = (range == 0) ? n0 : (range == 1) ? n0 - 2048 : n0 - 2560;
#pragma unroll
  for (int mt = 0; mt < 4; ++mt) {
    int row = m0 + wm * 64 + mt * 16 + quad * 4;
#pragma unroll
    for (int nt = 0; nt < 4; ++nt) {
      int col = nb + wn * 64 + nt * 16 + lr;
#pragma unroll
      for (int e = 0; e < 4; ++e)
        Cb[(size_t)(row + e) * ld + col] = (bf16)acc[mt][nt][e];
    }
  }
}

// ---------------------------------------------------------------------------
// O-projection GEMM: C[M,N] = A[M,K] @ W[N,K]^T, bf16, fp32 out.
// Same 2-phase counted-vmcnt dbuf as gemm_qkv range 0.
// ---------------------------------------------------------------------------
template <bool OUTF32>
__global__ __launch_bounds__(256) void gemm_bt(const bf16* __restrict__ Ap,
                                               const bf16* __restrict__ W,
                                               void* __restrict__ C0,
                                               int ld0, int M, int N, int K) {
  __shared__ alignas(16) bf16 As[2][16 * 512];
  __shared__ alignas(16) bf16 Bs[2][16 * 512];

  const int tid  = threadIdx.x;
  const int wave = tid >> 6, lane = tid & 63;
  const int wm = wave >> 1, wn = wave & 1;
  const int lr = lane & 15, quad = lane >> 4;
  const int m0 = blockIdx.y * 128, n0 = blockIdx.x * 128;
  const int NS = K >> 6;

  f32x4 vzero = {0.f, 0.f, 0.f, 0.f};
  f32x4 acc[4][4];
#pragma unroll
  for (int mt = 0; mt < 4; ++mt)
#pragma unroll
    for (int nt = 0; nt < 4; ++nt) acc[mt][nt] = vzero;

#define STAGE8(bufi, kk)                                                        \
  do {                                                                          \
    _Pragma("unroll") for (int j = 0; j < 4; ++j) {                             \
      int c = wave * 4 + j;                                                     \
      gl_lds16(W + (size_t)(n0 + (c >> 1) * 16 + lr) * K + (kk) +               \
                   (c & 1) * 32 + quad * 8,                                     \
               &Bs[bufi][c * 512]);                                             \
      gl_lds16(Ap + (size_t)(m0 + (c >> 1) * 16 + lr) * K + (kk) +              \
                   (c & 1) * 32 + quad * 8,                                     \
               &As[bufi][c * 512]);                                             \
    }                                                                           \
  } while (0)

  STAGE8(0, 0);
  int cur = 0;
  for (int t = 0; t < NS; ++t) {
    if (t + 1 < NS) {
      STAGE8(cur ^ 1, (t + 1) * 64);
      asm volatile("s_waitcnt vmcnt(8)" ::: "memory");
    } else {
      asm volatile("s_waitcnt vmcnt(0)" ::: "memory");
    }
    __builtin_amdgcn_s_barrier();
#pragma unroll
    for (int s = 0; s < 2; ++s) {
      bf16x8 af[4], bfg[4];
#pragma unroll
      for (int mt = 0; mt < 4; ++mt)
        af[mt] = *(const bf16x8*)(&As[cur][((wm * 4 + mt) * 2 + s) * 512] + lane * 8);
#pragma unroll
      for (int nt = 0; nt < 4; ++nt)
        bfg[nt] = *(const bf16x8*)(&Bs[cur][((wn * 4 + nt) * 2 + s) * 512] + lane * 8);
#pragma unroll
      for (int mt = 0; mt < 4; ++mt)
#pragma unroll
        for (int nt = 0; nt < 4; ++nt)
          acc[mt][nt] = MFMA16(af[mt], bfg[nt], acc[mt][nt]);
    }
    __builtin_amdgcn_s_barrier();
    cur ^= 1;
  }
#undef STAGE8

  // epilogue: C/D layout col = lane&15, row = quad*4 + e   [HW-verified m89]
#pragma unroll
  for (int mt = 0; mt < 4; ++mt) {
    int row = m0 + wm * 64 + mt * 16 + quad * 4;
#pragma unroll
    for (int nt = 0; nt < 4; ++nt) {
      int col = n0 + wn * 64 + nt * 16 + lr;
#pragma unroll
      for (int e = 0; e < 4; ++e) {
        if (OUTF32)
          ((float*)C0)[(size_t)(row + e) * ld0 + col] = acc[mt][nt][e];
        else
          ((bf16*)C0)[(size_t)(row + e) * ld0 + col] = (bf16)acc[mt][nt][e];
      }
    }
  }
}

// ---------------------------------------------------------------------------
// RoPE + clip (+scale fold), in place, vectorized: 8 (j,j+64) pairs/thread.
// ---------------------------------------------------------------------------
__global__ void rope_clip(bf16* __restrict__ X, int heads, float scl) {
  int tpr = heads * 8;
  int idx = blockIdx.x * 256 + threadIdx.x;
  if (idx >= 4096 * tpr) return;
  int r = idx / tpr;
  int rem = idx - r * tpr;
  int h = rem >> 3, j0 = (rem & 7) * 8;
  int l = r & 2047;
  size_t base = (size_t)r * (heads * 128) + h * 128 + j0;
  bf16x8 x1 = *(const bf16x8*)(X + base);
  bf16x8 x2 = *(const bf16x8*)(X + base + 64);
  bf16x8 y1, y2;
#pragma unroll
  for (int t = 0; t < 8; ++t) {
    int j = j0 + t;
    float inv = expf(-(float)j * (9.210340371976184f / 64.0f));
    float s, c;
    sincosf((float)l * inv, &s, &c);
    float a = (float)x1[t], b = (float)x2[t];
    float u = a * c - b * s;
    float v = a * s + b * c;
    y1[t] = (bf16)(fminf(fmaxf(u, -50.f), 50.f) * scl);
    y2[t] = (bf16)(fminf(fmaxf(v, -50.f), 50.f) * scl);
  }
  *(bf16x8*)(X + base)      = y1;
  *(bf16x8*)(X + base + 64) = y2;
}

// ---------------------------------------------------------------------------
// Transpose per batch: in (R x Cc) -> out (Cc x R).
// ---------------------------------------------------------------------------
__global__ void transpose_bf16(const bf16* __restrict__ in, bf16* __restrict__ out,
                               int R, int Cc) {
  __shared__ bf16 t[32][33];
  int b = blockIdx.z;
  const bf16* ip = in + (size_t)b * R * Cc;
  bf16* op = out + (size_t)b * R * Cc;
  int c0 = blockIdx.x * 32, r0 = blockIdx.y * 32;
  int lx = threadIdx.x, ly = threadIdx.y;
#pragma unroll
  for (int i = 0; i < 32; i += 8)
    t[ly + i][lx] = ip[(size_t)(r0 + ly + i) * Cc + c0 + lx];
  __syncthreads();
#pragma unroll
  for (int i = 0; i < 32; i += 8)
    op[(size_t)(c0 + ly + i) * R + r0 + lx] = t[lx][ly + i];
}

// ---------------------------------------------------------------------------
// Flash v6 (unchanged, verified): causal GQA, uniform-work paired blocks +
// 2-phase counted-vmcnt pipeline. 256 blocks = 1/CU, balanced.
// ---------------------------------------------------------------------------
__global__ __launch_bounds__(512, 2) void flash(const bf16* __restrict__ Q,
                                                const bf16* __restrict__ Kp,
                                                const bf16* __restrict__ Vt,
                                                bf16* __restrict__ Ctx) {
  __shared__ alignas(16) bf16 Ks[2][16 * 512];   // 2 x 16 KB
  __shared__ alignas(16) bf16 Vs[2][16 * 512];   // 2 x 16 KB
  __shared__ alignas(16) bf16 Ps[8][32 * 72];    // 36 KB

  const int tid  = threadIdx.x;
  const int wave = tid >> 6, lane = tid & 63;
  const int lr = lane & 15, quad = lane >> 4;
  const int bh = blockIdx.y;
  const int b = bh >> 4, h = bh & 15, hk = h >> 2;
  const int p = blockIdx.x;                     // 0..7 -> pair (p, 15-p)
  const int qA0 = p * 128, qB0 = (15 - p) * 128;
  const int qbA = qA0 + wave * 16;              // wave's rows in tile A
  const int qbB = qB0 + wave * 16;              // wave's rows in tile B
  const int nt = (qB0 + 128) >> 6;              // 32 - 2p chunk iterations

  // Q fragments for both tiles
  bf16x8 qfA[4], qfB[4];
  {
    const bf16* qa = Q + ((size_t)(b * 2048 + qbA + lr)) * 2048 + h * 128 + quad * 8;
    const bf16* qbp = Q + ((size_t)(b * 2048 + qbB + lr)) * 2048 + h * 128 + quad * 8;
#pragma unroll
    for (int ks = 0; ks < 4; ++ks) {
      qfA[ks] = *(const bf16x8*)(qa + ks * 32);
      qfB[ks] = *(const bf16x8*)(qbp + ks * 32);
    }
  }

  f32x4 vzero = {0.f, 0.f, 0.f, 0.f};
  f32x4 oA[8], oB[8];
#pragma unroll
  for (int dt = 0; dt < 8; ++dt) { oA[dt] = vzero; oB[dt] = vzero; }
  float flsA[4] = {0.f, 0.f, 0.f, 0.f};
  float flsB[4] = {0.f, 0.f, 0.f, 0.f};

  const bf16* kbase = Kp + (size_t)(b * 2048) * 512 + hk * 128;
  const bf16* vbase = Vt + ((size_t)(b * 512 + hk * 128)) * 2048;

  // stage 32 frag-chunks (16 K + 16 V), 4 per wave, fragment-ordered
#define STAGE(bufi, kk)                                                         \
  do {                                                                          \
    _Pragma("unroll") for (int j = 0; j < 4; ++j) {                             \
      int c = wave * 4 + j;                                                     \
      if (c < 16) {                                                             \
        gl_lds16(kbase + (size_t)((kk) + (c >> 2) * 16 + lr) * 512 +            \
                     (c & 3) * 32 + quad * 8,                                   \
                 &Ks[bufi][c * 512]);                                           \
      } else {                                                                  \
        int c2 = c - 16;                                                        \
        gl_lds16(vbase + (size_t)((c2 >> 1) * 16 + lr) * 2048 + (kk) +          \
                     (c2 & 1) * 32 + quad * 8,                                  \
                 &Vs[bufi][c2 * 512]);                                          \
      }                                                                         \
    }                                                                           \
  } while (0)

  STAGE(0, 0);  // prologue: chunk 0 -> buf 0
  int cur = 0;

  for (int t = 0; t < nt; ++t) {
    const int k0 = t * 64;
    if (t + 1 < nt) {
      STAGE(cur ^ 1, k0 + 64);  // issue next chunk before compute
      asm volatile("s_waitcnt vmcnt(4)" ::: "memory");  // wait prev chunk only
    } else {
      asm volatile("s_waitcnt vmcnt(0)" ::: "memory");
    }
    __builtin_amdgcn_s_barrier();   // all waves: chunk t fully staged

    const bf16* ksb = Ks[cur];
    const bf16* vsb = Vs[cur];

    if (k0 <= qbA + 15) {
      // ---- dual: tile A active => tile B active (and B never masked here) --
      f32x4 sA[4], sB[4];
#pragma unroll
      for (int kt = 0; kt < 4; ++kt) { sA[kt] = vzero; sB[kt] = vzero; }
#pragma unroll
      for (int ks = 0; ks < 4; ++ks) {
#pragma unroll
        for (int kt = 0; kt < 4; ++kt) {
          bf16x8 kf = *(const bf16x8*)(ksb + (kt * 4 + ks) * 512 + lane * 8);
          sA[kt] = MFMA16(qfA[ks], kf, sA[kt]);
          sB[kt] = MFMA16(qfB[ks], kf, sB[kt]);
        }
      }
      bf16* pwA = Ps[wave];
      bf16* pwB = Ps[wave] + 16 * 72;
#pragma unroll
      for (int kt = 0; kt < 4; ++kt) {
        int kid = k0 + kt * 16 + lr;
#pragma unroll
        for (int e = 0; e < 4; ++e) {
          int qr = quad * 4 + e;
          float pa = (kid <= qbA + qr) ? __expf(sA[kt][e]) : 0.f;
          float pb = __expf(sB[kt][e]);  // kid < 1024 <= qbB always
          flsA[e] += pa;
          flsB[e] += pb;
          pwA[qr * 72 + kt * 16 + lr] = (bf16)pa;
          pwB[qr * 72 + kt * 16 + lr] = (bf16)pb;
        }
      }
#pragma unroll
      for (int ks2 = 0; ks2 < 2; ++ks2) {
        bf16x8 pfA = *(const bf16x8*)(pwA + (size_t)lr * 72 + ks2 * 32 + quad * 8);
        bf16x8 pfB = *(const bf16x8*)(pwB + (size_t)lr * 72 + ks2 * 32 + quad * 8);
#pragma unroll
        for (int dt = 0; dt < 8; ++dt) {
          bf16x8 vf = *(const bf16x8*)(vsb + (dt * 2 + ks2) * 512 + lane * 8);
          oA[dt] = MFMA16(pfA, vf, oA[dt]);
          oB[dt] = MFMA16(pfB, vf, oB[dt]);
        }
      }
    } else if (k0 <= qbB + 15) {
      // ---- tile B only ----
      f32x4 s[4];
#pragma unroll
      for (int kt = 0; kt < 4; ++kt) s[kt] = vzero;
#pragma unroll
      for (int ks = 0; ks < 4; ++ks) {
#pragma unroll
        for (int kt = 0; kt < 4; ++kt) {
          bf16x8 kf = *(const bf16x8*)(ksb + (kt * 4 + ks) * 512 + lane * 8);
          s[kt] = MFMA16(qfB[ks], kf, s[kt]);
        }
      }
      bf16* pwB = Ps[wave] + 16 * 72;
#pragma unroll
      for (int kt = 0; kt < 4; ++kt) {
        int kid = k0 + kt * 16 + lr;
#pragma unroll
        for (int e = 0; e < 4; ++e) {
          int qr = quad * 4 + e;
          float pb = (kid <= qbB + qr) ? __expf(s[kt][e]) : 0.f;
          flsB[e] += pb;
          pwB[qr * 72 + kt * 16 + lr] = (bf16)pb;
        }
      }
#pragma unroll
      for (int ks2 = 0; ks2 < 2; ++ks2) {
        bf16x8 pf = *(const bf16x8*)(pwB + (size_t)lr * 72 + ks2 * 32 + quad * 8);
#pragma unroll
        for (int dt = 0; dt < 8; ++dt) {
          bf16x8 vf = *(const bf16x8*)(vsb + (dt * 2 + ks2) * 512 + lane * 8);
          oB[dt] = MFMA16(pf, vf, oB[dt]);
        }
      }
    }
    __builtin_amdgcn_s_barrier();   // all reads of buf[cur] done -> reusable
    cur ^= 1;
  }
#undef STAGE

  // denominator reduce across the 16 key-lanes
#pragma unroll
  for (int e = 0; e < 4; ++e) {
    float sa = flsA[e];
    sa += __shfl_xor(sa, 1);
    sa += __shfl_xor(sa, 2);
    sa += __shfl_xor(sa, 4);
    sa += __shfl_xor(sa, 8);
    flsA[e] = 1.0f / sa;
    float sb = flsB[e];
    sb += __shfl_xor(sb, 1);
    sb += __shfl_xor(sb, 2);
    sb += __shfl_xor(sb, 4);
    sb += __shfl_xor(sb, 8);
    flsB[e] = 1.0f / sb;
  }

  bf16* ca = Ctx + ((size_t)(b * 2048 + qbA + quad * 4)) * 2048 + h * 128 + lr;
  bf16* cb = Ctx + ((size_t)(b * 2048 + qbB + quad * 4)) * 2048 + h * 128 + lr;
#pragma unroll
  for (int dt = 0; dt < 8; ++dt)
#pragma unroll
    for (int e = 0; e < 4; ++e) {
      ca[(size_t)e * 2048 + dt * 16] = (bf16)(oA[dt][e] * flsA[e]);
      cb[(size_t)e * 2048 + dt * 16] = (bf16)(oB[dt][e] * flsB[e]);
    }
}

// ---------------------------------------------------------------------------
extern "C" void kernel_launch(void* const* d_in, const int* in_sizes, int n_in,
                              void* d_out, int out_size, void* d_ws, size_t ws_size,
                              hipStream_t stream) {
  (void)in_sizes; (void)n_in; (void)out_size; (void)ws_size;
  const float* query = (const float*)d_in[0];
  const float* key_t = (const float*)d_in[1];
  const float* value = (const float*)d_in[2];
  // d_in[3] = mask (causal tril) — applied analytically
  const float* Wq = (const float*)d_in[4];
  const float* Wk = (const float*)d_in[5];
  const float* Wv = (const float*)d_in[6];
  const float* Wo = (const float*)d_in[7];

  const size_t MB = 1024ull * 1024ull;
  char* ws  = (char*)d_ws;
  bf16* qbf = (bf16*)(ws);                  // [0,16)  query bf16
  bf16* wqb = (bf16*)(ws + 16 * MB);        // [16,24)  Wq bf16   (contiguous
  bf16* wkb = (bf16*)(ws + 24 * MB);        // [24,26)  Wk bf16    3072x2048
  bf16* wvb = (bf16*)(ws + 26 * MB);        // [26,28)  Wv bf16    W block)
  bf16* wob = (bf16*)(ws + 28 * MB);        // [28,36)
  bf16* Qb  = (bf16*)(ws + 36 * MB);        // [36,52)
  bf16* Kb  = (bf16*)(ws + 52 * MB);        // [52,56)
  bf16* Vb  = (bf16*)(ws + 56 * MB);        // [56,60)
  bf16* Vtb = (bf16*)(ws + 60 * MB);        // [60,64)
  bf16* Ctx = qbf;                          // alias: qbf dead after QKV-proj

  cvt_f32_bf16<<<4096, 256, 0, stream>>>(query, qbf, 1048576);
  cvt_f32_bf16<<<2048, 256, 0, stream>>>(Wq, wqb, 524288);
  cvt_f32_bf16<<<512, 256, 0, stream>>>(Wk, wkb, 131072);
  cvt_f32_bf16<<<512, 256, 0, stream>>>(Wv, wvb, 131072);
  cvt_f32_bf16<<<2048, 256, 0, stream>>>(Wo, wob, 524288);

  // FUSED Q+K+V projection: N=3072, 768 blocks, 2-phase pipelined
  gemm_qkv<<<dim3(24, 32), 256, 0, stream>>>(qbf, key_t, value, wqb, Qb, Kb, Vb);

  rope_clip<<<2048, 256, 0, stream>>>(Qb, 16, 0.08838834764831845f);
  rope_clip<<<512, 256, 0, stream>>>(Kb, 4, 1.0f);

  transpose_bf16<<<dim3(16, 64, 2), dim3(32, 8), 0, stream>>>(Vb, Vtb, 2048, 512);

  flash<<<dim3(8, 32), 512, 0, stream>>>(Qb, Kb, Vtb, Ctx);

  // O-projection: bf16 A (Ctx), fp32 output, 2-phase pipelined
  gemm_bt<true><<<dim3(16, 32), 256, 0, stream>>>(
      Ctx, wob, (float*)d_out, 2048, 4096, 2048, 2048);
}

// Round 6
// 431.529 us; speedup vs baseline: 1.0917x; 1.0901x over previous
//
#include <hip/hip_runtime.h>

typedef __bf16 bf16;
typedef __bf16 bf16x8 __attribute__((ext_vector_type(8)));
typedef float  f32x4  __attribute__((ext_vector_type(4)));

#define MFMA16(a, b, c) __builtin_amdgcn_mfma_f32_16x16x32_bf16((a), (b), (c), 0, 0, 0)

// async global->LDS, 16 B per lane: lane l -> ldsbase + l*16 (wave-uniform base).
__device__ inline void gl_lds16(const bf16* g, bf16* l) {
  __builtin_amdgcn_global_load_lds(
      (const __attribute__((address_space(1))) void*)g,
      (__attribute__((address_space(3))) void*)l, 16, 0, 0);
}

__device__ inline bf16x8 cvt8(const float* __restrict__ f) {
  float4 a = *(const float4*)f;
  float4 b = *(const float4*)(f + 4);
  bf16x8 r;
  r[0] = (bf16)a.x; r[1] = (bf16)a.y; r[2] = (bf16)a.z; r[3] = (bf16)a.w;
  r[4] = (bf16)b.x; r[5] = (bf16)b.y; r[6] = (bf16)b.z; r[7] = (bf16)b.w;
  return r;
}

// ---------------------------------------------------------------------------
__global__ void cvt_f32_bf16(const float* __restrict__ src, bf16* __restrict__ dst,
                             int n8) {
  int i = blockIdx.x * 256 + threadIdx.x;
  if (i >= n8) return;
  *(bf16x8*)(dst + (size_t)i * 8) = cvt8(src + (size_t)i * 8);
}

// ---------------------------------------------------------------------------
// FUSED QKV projection, 256x256 TILE, 8 waves (2M x 4N), BK=64.
// v8 post-mortem: per-K-step wall time is overhead-dominated and constant
// (pipelining + occupancy both NULL, matching learn_hip m131-m140/m233).
// The proven lever is work per K-step per CU: 256^2 = 512 MFMA/block/step
// (4x the 128^2 tile) amortizing the same per-step stage+wait+barrier cost
// (learn_hip: 128^2-2ph ~380-600 TF -> 256^2 682 -> 256^2-split-phase 1167).
// LDS fragment-ordered (frag_base + lane*16 reads): 0 bank conflicts by
// construction -> the st_16x32 swizzle (T2) is unnecessary here.
// Compute split into 4 quadrant phases, each {ds_read subtile -> setprio(1)
// 16 MFMA setprio(0)} (T5; pays on phase-split 256^2 per m218b/m224).
// Double-buffered, counted vmcnt(8). LDS 128 KB -> 1 block/CU, 2 waves/SIMD.
// A inputs all bf16 (key/value pre-converted).
// N = 3072 = 2048(Q) + 512(K) + 512(V); W = contiguous wqb|wkb|wvb rows.
// ---------------------------------------------------------------------------
__global__ __launch_bounds__(512, 2) void gemm_qkv256(const bf16* __restrict__ qA,
                                                      const bf16* __restrict__ kA,
                                                      const bf16* __restrict__ vA,
                                                      const bf16* __restrict__ W,
                                                      bf16* __restrict__ Qb,
                                                      bf16* __restrict__ Kb,
                                                      bf16* __restrict__ Vb) {
  __shared__ alignas(16) bf16 As[2][32 * 512];   // 2 x 32 KB, frag-ordered
  __shared__ alignas(16) bf16 Bs[2][32 * 512];   // 2 x 32 KB

  const int tid  = threadIdx.x;
  const int wave = tid >> 6, lane = tid & 63;
  const int wm = wave >> 2, wn = wave & 3;       // 2M x 4N wave grid
  const int lr = lane & 15, quad = lane >> 4;
  const int n0 = blockIdx.x * 256, m0 = blockIdx.y * 256;
  const int NS = 32;                             // K/BK = 2048/64

  const int range = (n0 < 2048) ? 0 : (n0 < 2560) ? 1 : 2;
  const bf16* Ab = (range == 0) ? qA : (range == 1) ? kA : vA;

  f32x4 vzero = {0.f, 0.f, 0.f, 0.f};
  f32x4 acc[8][4];
#pragma unroll
  for (int mt = 0; mt < 8; ++mt)
#pragma unroll
    for (int nt = 0; nt < 4; ++nt) acc[mt][nt] = vzero;

  // stage 64 frag-chunks (32 A + 32 B), 8 per wave.  Chunk c: row-block
  // mi=c>>1, k-slice s=c&1; lane l holds rows mi*16+(l&15),
  // cols k0+s*32+(l>>4)*8..+7  -> LDS linear at chunk*1KB + lane*16B.
#define STAGE256(bufi, kk)                                                      \
  do {                                                                          \
    _Pragma("unroll") for (int j = 0; j < 4; ++j) {                             \
      int c = wave * 4 + j;                                                     \
      int mi = c >> 1, sl = c & 1;                                              \
      gl_lds16(Ab + (size_t)(m0 + mi * 16 + lr) * 2048 + (kk) + sl * 32 + quad * 8, \
               &As[bufi][c * 512]);                                             \
      gl_lds16(W + (size_t)(n0 + mi * 16 + lr) * 2048 + (kk) + sl * 32 + quad * 8,  \
               &Bs[bufi][c * 512]);                                             \
    }                                                                           \
  } while (0)

  STAGE256(0, 0);
  int cur = 0;
  for (int t = 0; t < NS; ++t) {
    if (t + 1 < NS) {
      STAGE256(cur ^ 1, (t + 1) * 64);
      asm volatile("s_waitcnt vmcnt(8)" ::: "memory");  // tile t complete
    } else {
      asm volatile("s_waitcnt vmcnt(0)" ::: "memory");
    }
    __builtin_amdgcn_s_barrier();

    const bf16* as = As[cur];
    const bf16* bs = Bs[cur];
    bf16x8 af[4], bf0[4], bf1[4];

    // ---- phase 0: s=0, row-half 0 (mt 0..3) + load B s=0 ----
#pragma unroll
    for (int nt = 0; nt < 4; ++nt)
      bf0[nt] = *(const bf16x8*)(bs + ((wn * 4 + nt) * 2 + 0) * 512 + lane * 8);
#pragma unroll
    for (int mt = 0; mt < 4; ++mt)
      af[mt] = *(const bf16x8*)(as + ((wm * 8 + mt) * 2 + 0) * 512 + lane * 8);
    __builtin_amdgcn_s_setprio(1);
#pragma unroll
    for (int mt = 0; mt < 4; ++mt)
#pragma unroll
      for (int nt = 0; nt < 4; ++nt)
        acc[mt][nt] = MFMA16(af[mt], bf0[nt], acc[mt][nt]);
    __builtin_amdgcn_s_setprio(0);

    // ---- phase 1: s=0, row-half 1 (mt 4..7), reuse bf0 ----
#pragma unroll
    for (int mt = 0; mt < 4; ++mt)
      af[mt] = *(const bf16x8*)(as + ((wm * 8 + 4 + mt) * 2 + 0) * 512 + lane * 8);
    __builtin_amdgcn_s_setprio(1);
#pragma unroll
    for (int mt = 0; mt < 4; ++mt)
#pragma unroll
      for (int nt = 0; nt < 4; ++nt)
        acc[4 + mt][nt] = MFMA16(af[mt], bf0[nt], acc[4 + mt][nt]);
    __builtin_amdgcn_s_setprio(0);

    // ---- phase 2: s=1, row-half 0 + load B s=1 ----
#pragma unroll
    for (int nt = 0; nt < 4; ++nt)
      bf1[nt] = *(const bf16x8*)(bs + ((wn * 4 + nt) * 2 + 1) * 512 + lane * 8);
#pragma unroll
    for (int mt = 0; mt < 4; ++mt)
      af[mt] = *(const bf16x8*)(as + ((wm * 8 + mt) * 2 + 1) * 512 + lane * 8);
    __builtin_amdgcn_s_setprio(1);
#pragma unroll
    for (int mt = 0; mt < 4; ++mt)
#pragma unroll
      for (int nt = 0; nt < 4; ++nt)
        acc[mt][nt] = MFMA16(af[mt], bf1[nt], acc[mt][nt]);
    __builtin_amdgcn_s_setprio(0);

    // ---- phase 3: s=1, row-half 1, reuse bf1 ----
#pragma unroll
    for (int mt = 0; mt < 4; ++mt)
      af[mt] = *(const bf16x8*)(as + ((wm * 8 + 4 + mt) * 2 + 1) * 512 + lane * 8);
    __builtin_amdgcn_s_setprio(1);
#pragma unroll
    for (int mt = 0; mt < 4; ++mt)
#pragma unroll
      for (int nt = 0; nt < 4; ++nt)
        acc[4 + mt][nt] = MFMA16(af[mt], bf1[nt], acc[4 + mt][nt]);
    __builtin_amdgcn_s_setprio(0);

    __builtin_amdgcn_s_barrier();   // all reads of buf[cur] done -> reusable
    cur ^= 1;
  }
#undef STAGE256

  // epilogue: C/D layout col = lane&15, row = quad*4 + e   [HW-verified m89]
  bf16* Cb = (range == 0) ? Qb : (range == 1) ? Kb : Vb;
  const int ld = (range == 0) ? 2048 : 512;
  const int nb = (range == 0) ? n0 : (range == 1) ? n0 - 2048 : n0 - 2560;
#pragma unroll
  for (int mt = 0; mt < 8; ++mt) {
    int row = m0 + wm * 128 + mt * 16 + quad * 4;
#pragma unroll
    for (int nt = 0; nt < 4; ++nt) {
      int col = nb + wn * 64 + nt * 16 + lr;
#pragma unroll
      for (int e = 0; e < 4; ++e)
        Cb[(size_t)(row + e) * ld + col] = (bf16)acc[mt][nt][e];
    }
  }
}

// ---------------------------------------------------------------------------
// O-projection GEMM: C[M,N] = A[M,K] @ W[N,K]^T, bf16, fp32 out.
// 128x128 2-phase counted-vmcnt dbuf (kept: 256 blocks = 1/CU full fill;
// 256^2 here would give 128 blocks = half the machine idle).
// ---------------------------------------------------------------------------
template <bool OUTF32>
__global__ __launch_bounds__(256) void gemm_bt(const bf16* __restrict__ Ap,
                                               const bf16* __restrict__ W,
                                               void* __restrict__ C0,
                                               int ld0, int M, int N, int K) {
  __shared__ alignas(16) bf16 As[2][16 * 512];
  __shared__ alignas(16) bf16 Bs[2][16 * 512];

  const int tid  = threadIdx.x;
  const int wave = tid >> 6, lane = tid & 63;
  const int wm = wave >> 1, wn = wave & 1;
  const int lr = lane & 15, quad = lane >> 4;
  const int m0 = blockIdx.y * 128, n0 = blockIdx.x * 128;
  const int NS = K >> 6;

  f32x4 vzero = {0.f, 0.f, 0.f, 0.f};
  f32x4 acc[4][4];
#pragma unroll
  for (int mt = 0; mt < 4; ++mt)
#pragma unroll
    for (int nt = 0; nt < 4; ++nt) acc[mt][nt] = vzero;

#define STAGE8(bufi, kk)                                                        \
  do {                                                                          \
    _Pragma("unroll") for (int j = 0; j < 4; ++j) {                             \
      int c = wave * 4 + j;                                                     \
      gl_lds16(W + (size_t)(n0 + (c >> 1) * 16 + lr) * K + (kk) +               \
                   (c & 1) * 32 + quad * 8,                                     \
               &Bs[bufi][c * 512]);                                             \
      gl_lds16(Ap + (size_t)(m0 + (c >> 1) * 16 + lr) * K + (kk) +              \
                   (c & 1) * 32 + quad * 8,                                     \
               &As[bufi][c * 512]);                                             \
    }                                                                           \
  } while (0)

  STAGE8(0, 0);
  int cur = 0;
  for (int t = 0; t < NS; ++t) {
    if (t + 1 < NS) {
      STAGE8(cur ^ 1, (t + 1) * 64);
      asm volatile("s_waitcnt vmcnt(8)" ::: "memory");
    } else {
      asm volatile("s_waitcnt vmcnt(0)" ::: "memory");
    }
    __builtin_amdgcn_s_barrier();
#pragma unroll
    for (int s = 0; s < 2; ++s) {
      bf16x8 af[4], bfg[4];
#pragma unroll
      for (int mt = 0; mt < 4; ++mt)
        af[mt] = *(const bf16x8*)(&As[cur][((wm * 4 + mt) * 2 + s) * 512] + lane * 8);
#pragma unroll
      for (int nt = 0; nt < 4; ++nt)
        bfg[nt] = *(const bf16x8*)(&Bs[cur][((wn * 4 + nt) * 2 + s) * 512] + lane * 8);
      __builtin_amdgcn_s_setprio(1);
#pragma unroll
      for (int mt = 0; mt < 4; ++mt)
#pragma unroll
        for (int nt = 0; nt < 4; ++nt)
          acc[mt][nt] = MFMA16(af[mt], bfg[nt], acc[mt][nt]);
      __builtin_amdgcn_s_setprio(0);
    }
    __builtin_amdgcn_s_barrier();
    cur ^= 1;
  }
#undef STAGE8

  // epilogue: C/D layout col = lane&15, row = quad*4 + e   [HW-verified m89]
#pragma unroll
  for (int mt = 0; mt < 4; ++mt) {
    int row = m0 + wm * 64 + mt * 16 + quad * 4;
#pragma unroll
    for (int nt = 0; nt < 4; ++nt) {
      int col = n0 + wn * 64 + nt * 16 + lr;
#pragma unroll
      for (int e = 0; e < 4; ++e) {
        if (OUTF32)
          ((float*)C0)[(size_t)(row + e) * ld0 + col] = acc[mt][nt][e];
        else
          ((bf16*)C0)[(size_t)(row + e) * ld0 + col] = (bf16)acc[mt][nt][e];
      }
    }
  }
}

// ---------------------------------------------------------------------------
// RoPE + clip (+scale fold), in place, vectorized: 8 (j,j+64) pairs/thread.
// ---------------------------------------------------------------------------
__global__ void rope_clip(bf16* __restrict__ X, int heads, float scl) {
  int tpr = heads * 8;
  int idx = blockIdx.x * 256 + threadIdx.x;
  if (idx >= 4096 * tpr) return;
  int r = idx / tpr;
  int rem = idx - r * tpr;
  int h = rem >> 3, j0 = (rem & 7) * 8;
  int l = r & 2047;
  size_t base = (size_t)r * (heads * 128) + h * 128 + j0;
  bf16x8 x1 = *(const bf16x8*)(X + base);
  bf16x8 x2 = *(const bf16x8*)(X + base + 64);
  bf16x8 y1, y2;
#pragma unroll
  for (int t = 0; t < 8; ++t) {
    int j = j0 + t;
    float inv = expf(-(float)j * (9.210340371976184f / 64.0f));
    float s, c;
    sincosf((float)l * inv, &s, &c);
    float a = (float)x1[t], b = (float)x2[t];
    float u = a * c - b * s;
    float v = a * s + b * c;
    y1[t] = (bf16)(fminf(fmaxf(u, -50.f), 50.f) * scl);
    y2[t] = (bf16)(fminf(fmaxf(v, -50.f), 50.f) * scl);
  }
  *(bf16x8*)(X + base)      = y1;
  *(bf16x8*)(X + base + 64) = y2;
}

// ---------------------------------------------------------------------------
// Transpose per batch: in (R x Cc) -> out (Cc x R).
// ---------------------------------------------------------------------------
__global__ void transpose_bf16(const bf16* __restrict__ in, bf16* __restrict__ out,
                               int R, int Cc) {
  __shared__ bf16 t[32][33];
  int b = blockIdx.z;
  const bf16* ip = in + (size_t)b * R * Cc;
  bf16* op = out + (size_t)b * R * Cc;
  int c0 = blockIdx.x * 32, r0 = blockIdx.y * 32;
  int lx = threadIdx.x, ly = threadIdx.y;
#pragma unroll
  for (int i = 0; i < 32; i += 8)
    t[ly + i][lx] = ip[(size_t)(r0 + ly + i) * Cc + c0 + lx];
  __syncthreads();
#pragma unroll
  for (int i = 0; i < 32; i += 8)
    op[(size_t)(c0 + ly + i) * R + r0 + lx] = t[lx][ly + i];
}

// ---------------------------------------------------------------------------
// Flash v6 (unchanged, verified): causal GQA, uniform-work paired blocks +
// 2-phase counted-vmcnt pipeline. 256 blocks = 1/CU, balanced.
// ---------------------------------------------------------------------------
__global__ __launch_bounds__(512, 2) void flash(const bf16* __restrict__ Q,
                                                const bf16* __restrict__ Kp,
                                                const bf16* __restrict__ Vt,
                                                bf16* __restrict__ Ctx) {
  __shared__ alignas(16) bf16 Ks[2][16 * 512];   // 2 x 16 KB
  __shared__ alignas(16) bf16 Vs[2][16 * 512];   // 2 x 16 KB
  __shared__ alignas(16) bf16 Ps[8][32 * 72];    // 36 KB

  const int tid  = threadIdx.x;
  const int wave = tid >> 6, lane = tid & 63;
  const int lr = lane & 15, quad = lane >> 4;
  const int bh = blockIdx.y;
  const int b = bh >> 4, h = bh & 15, hk = h >> 2;
  const int p = blockIdx.x;                     // 0..7 -> pair (p, 15-p)
  const int qA0 = p * 128, qB0 = (15 - p) * 128;
  const int qbA = qA0 + wave * 16;              // wave's rows in tile A
  const int qbB = qB0 + wave * 16;              // wave's rows in tile B
  const int nt = (qB0 + 128) >> 6;              // 32 - 2p chunk iterations

  // Q fragments for both tiles
  bf16x8 qfA[4], qfB[4];
  {
    const bf16* qa = Q + ((size_t)(b * 2048 + qbA + lr)) * 2048 + h * 128 + quad * 8;
    const bf16* qbp = Q + ((size_t)(b * 2048 + qbB + lr)) * 2048 + h * 128 + quad * 8;
#pragma unroll
    for (int ks = 0; ks < 4; ++ks) {
      qfA[ks] = *(const bf16x8*)(qa + ks * 32);
      qfB[ks] = *(const bf16x8*)(qbp + ks * 32);
    }
  }

  f32x4 vzero = {0.f, 0.f, 0.f, 0.f};
  f32x4 oA[8], oB[8];
#pragma unroll
  for (int dt = 0; dt < 8; ++dt) { oA[dt] = vzero; oB[dt] = vzero; }
  float flsA[4] = {0.f, 0.f, 0.f, 0.f};
  float flsB[4] = {0.f, 0.f, 0.f, 0.f};

  const bf16* kbase = Kp + (size_t)(b * 2048) * 512 + hk * 128;
  const bf16* vbase = Vt + ((size_t)(b * 512 + hk * 128)) * 2048;

  // stage 32 frag-chunks (16 K + 16 V), 4 per wave, fragment-ordered
#define STAGE(bufi, kk)                                                         \
  do {                                                                          \
    _Pragma("unroll") for (int j = 0; j < 4; ++j) {                             \
      int c = wave * 4 + j;                                                     \
      if (c < 16) {                                                             \
        gl_lds16(kbase + (size_t)((kk) + (c >> 2) * 16 + lr) * 512 +            \
                     (c & 3) * 32 + quad * 8,                                   \
                 &Ks[bufi][c * 512]);                                           \
      } else {                                                                  \
        int c2 = c - 16;                                                        \
        gl_lds16(vbase + (size_t)((c2 >> 1) * 16 + lr) * 2048 + (kk) +          \
                     (c2 & 1) * 32 + quad * 8,                                  \
                 &Vs[bufi][c2 * 512]);                                          \
      }                                                                         \
    }                                                                           \
  } while (0)

  STAGE(0, 0);  // prologue: chunk 0 -> buf 0
  int cur = 0;

  for (int t = 0; t < nt; ++t) {
    const int k0 = t * 64;
    if (t + 1 < nt) {
      STAGE(cur ^ 1, k0 + 64);  // issue next chunk before compute
      asm volatile("s_waitcnt vmcnt(4)" ::: "memory");  // wait prev chunk only
    } else {
      asm volatile("s_waitcnt vmcnt(0)" ::: "memory");
    }
    __builtin_amdgcn_s_barrier();   // all waves: chunk t fully staged

    const bf16* ksb = Ks[cur];
    const bf16* vsb = Vs[cur];

    if (k0 <= qbA + 15) {
      // ---- dual: tile A active => tile B active (and B never masked here) --
      f32x4 sA[4], sB[4];
#pragma unroll
      for (int kt = 0; kt < 4; ++kt) { sA[kt] = vzero; sB[kt] = vzero; }
#pragma unroll
      for (int ks = 0; ks < 4; ++ks) {
#pragma unroll
        for (int kt = 0; kt < 4; ++kt) {
          bf16x8 kf = *(const bf16x8*)(ksb + (kt * 4 + ks) * 512 + lane * 8);
          sA[kt] = MFMA16(qfA[ks], kf, sA[kt]);
          sB[kt] = MFMA16(qfB[ks], kf, sB[kt]);
        }
      }
      bf16* pwA = Ps[wave];
      bf16* pwB = Ps[wave] + 16 * 72;
#pragma unroll
      for (int kt = 0; kt < 4; ++kt) {
        int kid = k0 + kt * 16 + lr;
#pragma unroll
        for (int e = 0; e < 4; ++e) {
          int qr = quad * 4 + e;
          float pa = (kid <= qbA + qr) ? __expf(sA[kt][e]) : 0.f;
          float pb = __expf(sB[kt][e]);  // kid < 1024 <= qbB always
          flsA[e] += pa;
          flsB[e] += pb;
          pwA[qr * 72 + kt * 16 + lr] = (bf16)pa;
          pwB[qr * 72 + kt * 16 + lr] = (bf16)pb;
        }
      }
#pragma unroll
      for (int ks2 = 0; ks2 < 2; ++ks2) {
        bf16x8 pfA = *(const bf16x8*)(pwA + (size_t)lr * 72 + ks2 * 32 + quad * 8);
        bf16x8 pfB = *(const bf16x8*)(pwB + (size_t)lr * 72 + ks2 * 32 + quad * 8);
#pragma unroll
        for (int dt = 0; dt < 8; ++dt) {
          bf16x8 vf = *(const bf16x8*)(vsb + (dt * 2 + ks2) * 512 + lane * 8);
          oA[dt] = MFMA16(pfA, vf, oA[dt]);
          oB[dt] = MFMA16(pfB, vf, oB[dt]);
        }
      }
    } else if (k0 <= qbB + 15) {
      // ---- tile B only ----
      f32x4 s[4];
#pragma unroll
      for (int kt = 0; kt < 4; ++kt) s[kt] = vzero;
#pragma unroll
      for (int ks = 0; ks < 4; ++ks) {
#pragma unroll
        for (int kt = 0; kt < 4; ++kt) {
          bf16x8 kf = *(const bf16x8*)(ksb + (kt * 4 + ks) * 512 + lane * 8);
          s[kt] = MFMA16(qfB[ks], kf, s[kt]);
        }
      }
      bf16* pwB = Ps[wave] + 16 * 72;
#pragma unroll
      for (int kt = 0; kt < 4; ++kt) {
        int kid = k0 + kt * 16 + lr;
#pragma unroll
        for (int e = 0; e < 4; ++e) {
          int qr = quad * 4 + e;
          float pb = (kid <= qbB + qr) ? __expf(s[kt][e]) : 0.f;
          flsB[e] += pb;
          pwB[qr * 72 + kt * 16 + lr] = (bf16)pb;
        }
      }
#pragma unroll
      for (int ks2 = 0; ks2 < 2; ++ks2) {
        bf16x8 pf = *(const bf16x8*)(pwB + (size_t)lr * 72 + ks2 * 32 + quad * 8);
#pragma unroll
        for (int dt = 0; dt < 8; ++dt) {
          bf16x8 vf = *(const bf16x8*)(vsb + (dt * 2 + ks2) * 512 + lane * 8);
          oB[dt] = MFMA16(pf, vf, oB[dt]);
        }
      }
    }
    __builtin_amdgcn_s_barrier();   // all reads of buf[cur] done -> reusable
    cur ^= 1;
  }
#undef STAGE

  // denominator reduce across the 16 key-lanes
#pragma unroll
  for (int e = 0; e < 4; ++e) {
    float sa = flsA[e];
    sa += __shfl_xor(sa, 1);
    sa += __shfl_xor(sa, 2);
    sa += __shfl_xor(sa, 4);
    sa += __shfl_xor(sa, 8);
    flsA[e] = 1.0f / sa;
    float sb = flsB[e];
    sb += __shfl_xor(sb, 1);
    sb += __shfl_xor(sb, 2);
    sb += __shfl_xor(sb, 4);
    sb += __shfl_xor(sb, 8);
    flsB[e] = 1.0f / sb;
  }

  bf16* ca = Ctx + ((size_t)(b * 2048 + qbA + quad * 4)) * 2048 + h * 128 + lr;
  bf16* cb = Ctx + ((size_t)(b * 2048 + qbB + quad * 4)) * 2048 + h * 128 + lr;
#pragma unroll
  for (int dt = 0; dt < 8; ++dt)
#pragma unroll
    for (int e = 0; e < 4; ++e) {
      ca[(size_t)e * 2048 + dt * 16] = (bf16)(oA[dt][e] * flsA[e]);
      cb[(size_t)e * 2048 + dt * 16] = (bf16)(oB[dt][e] * flsB[e]);
    }
}

// ---------------------------------------------------------------------------
extern "C" void kernel_launch(void* const* d_in, const int* in_sizes, int n_in,
                              void* d_out, int out_size, void* d_ws, size_t ws_size,
                              hipStream_t stream) {
  (void)in_sizes; (void)n_in; (void)out_size; (void)ws_size;
  const float* query = (const float*)d_in[0];
  const float* key_t = (const float*)d_in[1];
  const float* value = (const float*)d_in[2];
  // d_in[3] = mask (causal tril) — applied analytically
  const float* Wq = (const float*)d_in[4];
  const float* Wk = (const float*)d_in[5];
  const float* Wv = (const float*)d_in[6];
  const float* Wo = (const float*)d_in[7];

  const size_t MB = 1024ull * 1024ull;
  char* ws  = (char*)d_ws;
  bf16* qbf = (bf16*)(ws);                  // [0,16)  query bf16
  bf16* wqb = (bf16*)(ws + 16 * MB);        // [16,24)  Wq bf16   (contiguous
  bf16* wkb = (bf16*)(ws + 24 * MB);        // [24,26)  Wk bf16    3072x2048
  bf16* wvb = (bf16*)(ws + 26 * MB);        // [26,28)  Wv bf16    W block)
  bf16* wob = (bf16*)(ws + 28 * MB);        // [28,36)
  bf16* Qb  = (bf16*)(ws + 36 * MB);        // [36,52)
  bf16* Kb  = (bf16*)(ws + 52 * MB);        // [52,56)
  bf16* Vb  = (bf16*)(ws + 56 * MB);        // [56,60)
  bf16* Vtb = (bf16*)(ws + 60 * MB);        // [60,64)
  bf16* kb16 = (bf16*)(ws + 64 * MB);       // [64,80)  key_t bf16
  bf16* vb16 = (bf16*)(ws + 80 * MB);       // [80,96)  value bf16
  bf16* Ctx = qbf;                          // alias: qbf dead after QKV-proj

  cvt_f32_bf16<<<4096, 256, 0, stream>>>(query, qbf, 1048576);
  cvt_f32_bf16<<<4096, 256, 0, stream>>>(key_t, kb16, 1048576);
  cvt_f32_bf16<<<4096, 256, 0, stream>>>(value, vb16, 1048576);
  cvt_f32_bf16<<<2048, 256, 0, stream>>>(Wq, wqb, 524288);
  cvt_f32_bf16<<<512, 256, 0, stream>>>(Wk, wkb, 131072);
  cvt_f32_bf16<<<512, 256, 0, stream>>>(Wv, wvb, 131072);
  cvt_f32_bf16<<<2048, 256, 0, stream>>>(Wo, wob, 524288);

  // FUSED Q+K+V projection: 256^2 tile, N=3072, grid 12x16 = 192 blocks
  gemm_qkv256<<<dim3(12, 16), 512, 0, stream>>>(qbf, kb16, vb16, wqb, Qb, Kb, Vb);

  rope_clip<<<2048, 256, 0, stream>>>(Qb, 16, 0.08838834764831845f);
  rope_clip<<<512, 256, 0, stream>>>(Kb, 4, 1.0f);

  transpose_bf16<<<dim3(16, 64, 2), dim3(32, 8), 0, stream>>>(Vb, Vtb, 2048, 512);

  flash<<<dim3(8, 32), 512, 0, stream>>>(Qb, Kb, Vtb, Ctx);

  // O-projection: bf16 A (Ctx), fp32 output, 128^2 2-phase (full grid fill)
  gemm_bt<true><<<dim3(16, 32), 256, 0, stream>>>(
      Ctx, wob, (float*)d_out, 2048, 4096, 2048, 2048);
}